// Round 9
// baseline (51.493 us; speedup 1.0000x reference)
//
#include <hip/hip_runtime.h>

// LocalDecoder: per-edge gather + 2 stacked MLPs (256->64->64->1).
// R9 design: 32x32x16 MFMA, edges on N=32, f-split waves (wave&1 = feature),
// FULL per-f weight set held in registers (128 regs, unified VGPR/AGPR file),
// bias folded in as a constant-1.0 input channel (K1=176, K2=80).
// Loop LDS traffic: 8 ds_read_b128 (w3 only). No hbf/ea0 prep passes.
//
// ws layout (bytes):
//   OFF_W1: bf16 W1frag[2][11][2][64][8] = 45056   (f, kk, mm, lane, j)
//   OFF_W2: bf16 W2frag[2][5][2][64][8]  = 20480
//   OFF_W3: f32 w3[2][64] = 512;  OFF_B3: f32 b3[2]
// K1 channels: [0:128) nodes, [128:160) enc_local, 160 = bias-one, rest 0.
// K2 channels: [0:64) h1, 64 = bias-one, rest 0.

#define OFF_W1 0
#define OFF_W2 45056
#define OFF_W3 65536
#define OFF_B3 66048
#define WS_NEED 66056
#define NWAVE 8

typedef __attribute__((ext_vector_type(8))) short bf16x8;
typedef __attribute__((ext_vector_type(4))) float f32x4;
typedef __attribute__((ext_vector_type(16))) float f32x16;

__device__ inline short f2bf(float f) {                  // prep-side scalar RNE
    unsigned u = __builtin_bit_cast(unsigned, f);
    u += 0x7FFFu + ((u >> 16) & 1u);
    return (short)(u >> 16);
}

__device__ inline float4 ld4(const float* p, bool v) {
    if (v) return *(const float4*)p;
    return make_float4(0.f, 0.f, 0.f, 0.f);
}

__device__ inline unsigned cvt_pk(float lo, float hi) {  // 2xf32 -> packed 2xbf16 (RNE)
    unsigned r;
    asm("v_cvt_pk_bf16_f32 %0, %1, %2" : "=v"(r) : "v"(lo), "v"(hi));
    return r;
}

__device__ inline bf16x8 pack8(float4 a, float4 b) {
    union { bf16x8 v; unsigned u[4]; } r;
    r.u[0] = cvt_pk(a.x, a.y);
    r.u[1] = cvt_pk(a.z, a.w);
    r.u[2] = cvt_pk(b.x, b.y);
    r.u[3] = cvt_pk(b.z, b.w);
    return r.v;
}

__device__ inline float lrelu(float x) { return fmaxf(x, 0.01f * x); }

// ---------------- prep: W swizzle with bias channels (tiny, ~1us)
__global__ void prep_w(const float* __restrict__ W1, const float* __restrict__ b1,
                       const float* __restrict__ W2, const float* __restrict__ b2,
                       const float* __restrict__ W3, const float* __restrict__ b3,
                       const float* __restrict__ h_global, const float* __restrict__ enc_global,
                       char* __restrict__ ws) {
    int idx = blockIdx.x * 256 + threadIdx.x;
    if (idx < 22528) {                       // W1 frags: out=32mm+(l&31), kt=16kk+8(l>>5)+j
        int f = idx / 11264, r0 = idx % 11264;
        int r1 = r0 % 1024;                  // kk = r0/1024 encoded in idx position
        int l = (r1 % 512) / 8, j = r1 % 8;
        int kk = r0 / 1024;
        int mm = r1 / 512;
        int kt = kk * 16 + (l >> 5) * 8 + j;
        int out = mm * 32 + (l & 31);
        float v;
        if (kt < 128)       v = W1[(f * 256 + kt) * 64 + out];
        else if (kt < 160)  v = W1[(f * 256 + kt + 64) * 64 + out];  // enc rows 192..223
        else if (kt == 160) {                // folded bias channel
            float s = b1[f * 64 + out];
            for (int t = 0; t < 64; ++t) s += h_global[t] * W1[(f * 256 + 128 + t) * 64 + out];
            for (int t = 0; t < 32; ++t) s += enc_global[t] * W1[(f * 256 + 224 + t) * 64 + out];
            v = s;
        } else v = 0.f;
        ((short*)(ws + OFF_W1))[idx] = f2bf(v);
    } else if (idx < 32768) {                // W2 frags: k2=16kk2+8(l>>5)+j
        int i2 = idx - 22528;
        int f = i2 / 5120, r0 = i2 % 5120;
        int r1 = r0 % 1024;
        int l = (r1 % 512) / 8, j = r1 % 8;
        int kk2 = r0 / 1024;
        int mm = r1 / 512;
        int k2 = kk2 * 16 + (l >> 5) * 8 + j;
        int out = mm * 32 + (l & 31);
        float v;
        if (k2 < 64)       v = W2[(f * 64 + k2) * 64 + out];
        else if (k2 == 64) v = b2[f * 64 + out];
        else               v = 0.f;
        ((short*)(ws + OFF_W2))[i2] = f2bf(v);
    } else if (idx < 32896) {
        int i = idx - 32768;
        ((float*)(ws + OFF_W3))[i] = W3[i];  // W3 is [2][64][1]
    } else if (idx < 32898) {
        ((float*)(ws + OFF_B3))[idx - 32896] = b3[idx - 32896];
    }
}

// ---------------- main: persistent, 8 waves/block, wave pair (2t,2t+1) = one
// 32-edge tile x {f=0,f=1}; weights in regs; D[out][edge], edge=lane&31.
__global__ __launch_bounds__(512, 2) void main_kernel(
        const float* __restrict__ edge_array, const float* __restrict__ h_local,
        const float* __restrict__ enc_local,
        const int* __restrict__ addr_from, const int* __restrict__ addr_to,
        const char* __restrict__ ws, float* __restrict__ out,
        int n_edges, int n_nodes) {
    __shared__ __align__(16) float w3s[130];
    const int tid = threadIdx.x;
    const int lane = tid & 63, wave = tid >> 6;
    const int col = lane & 31, hi = lane >> 5;
    const int f = wave & 1;
    const int ntiles = (n_edges + 31) >> 5;
    const int stride = (gridDim.x * NWAVE) >> 1;

    if (tid < 130) w3s[tid] = ((const float*)(ws + OFF_W3))[tid];  // w3[2][64] + b3[2]

    // one-time: per-f weight fragments -> registers (coalesced 16B/lane)
    bf16x8 w1r[22], w2r[10];
    {
        const char* b1p = ws + OFF_W1 + (size_t)f * 22 * 1024 + lane * 16;
        #pragma unroll
        for (int i = 0; i < 22; ++i) w1r[i] = *(const bf16x8*)(b1p + i * 1024);
        const char* b2p = ws + OFF_W2 + (size_t)f * 10 * 1024 + lane * 16;
        #pragma unroll
        for (int i = 0; i < 10; ++i) w2r[i] = *(const bf16x8*)(b2p + i * 1024);
    }
    __syncthreads();
    const float b3v = w3s[128 + f];

    bf16x8 cfrag;                                        // constant-1.0 bias channel frag
    {
        union { bf16x8 v; unsigned u[4]; } c;
        c.u[0] = (hi == 0) ? 0x00003F80u : 0u;           // bf16(1.0) at j=0, hi=0
        c.u[1] = 0u; c.u[2] = 0u; c.u[3] = 0u;
        cfrag = c.v;
    }

    int t = (blockIdx.x * NWAVE + wave) >> 1;
    int af = 0, at = 0;
    if (t < ntiles) {                                    // index prefetch
        int e0 = t * 32 + col; if (e0 >= n_edges) e0 = n_edges - 1;
        af = addr_from[e0]; at = addr_to[e0];
    }

    while (t < ntiles) {
        int tb = t * 32;
        int ec = tb + col; if (ec >= n_edges) ec = n_edges - 1;

        // ---- gather f32 + pack -> bf16 frags (k = 16kk + 8hi + j)
        bool afv = (unsigned)af < (unsigned)n_nodes;
        bool atv = (unsigned)at < (unsigned)n_nodes;
        const float* pf = h_local + (size_t)(afv ? af : 0) * 64 + hi * 8;
        const float* pt = h_local + (size_t)(atv ? at : 0) * 64 + hi * 8;
        const float* pe = enc_local + (size_t)ec * 32 + hi * 8;
        bf16x8 a1[11];
        #pragma unroll
        for (int kk = 0; kk < 4; ++kk) {
            a1[kk]     = pack8(ld4(pf + 16 * kk, afv), ld4(pf + 16 * kk + 4, afv));
            a1[kk + 4] = pack8(ld4(pt + 16 * kk, atv), ld4(pt + 16 * kk + 4, atv));
        }
        a1[8] = pack8(*(const float4*)pe,        *(const float4*)(pe + 4));
        a1[9] = pack8(*(const float4*)(pe + 16), *(const float4*)(pe + 20));
        a1[10] = cfrag;
        float ea = edge_array[4 * (size_t)ec];

        // prefetch next iteration's indices (hides addr->node chain)
        int tn = t + stride;
        int af2 = 0, at2 = 0;
        if (tn < ntiles) {
            int e2 = tn * 32 + col; if (e2 >= n_edges) e2 = n_edges - 1;
            af2 = addr_from[e2]; at2 = addr_to[e2];
        }

        // ---- layer 1 (K=176, bias via channel 160), zero-init acc
        f32x16 acc[2];
        #pragma unroll
        for (int mm = 0; mm < 2; ++mm)
            #pragma unroll
            for (int i = 0; i < 16; ++i) acc[mm][i] = 0.f;
        #pragma unroll
        for (int kk = 0; kk < 11; ++kk)
            #pragma unroll
            for (int mm = 0; mm < 2; ++mm)
                acc[mm] = __builtin_amdgcn_mfma_f32_32x32x16_bf16(w1r[kk * 2 + mm], a1[kk], acc[mm], 0, 0, 0);

        // lrelu + pack rows: pk[mm][i] = rows (2i, 2i+1)
        unsigned pk[2][8];
        #pragma unroll
        for (int mm = 0; mm < 2; ++mm)
            #pragma unroll
            for (int i = 0; i < 8; ++i)
                pk[mm][i] = cvt_pk(lrelu(acc[mm][2 * i]), lrelu(acc[mm][2 * i + 1]));

        // ---- layer 2 (K=80): lane-pair redistribution + const bias frag
        #pragma unroll
        for (int mm = 0; mm < 2; ++mm)
            #pragma unroll
            for (int i = 0; i < 16; ++i) acc[mm][i] = 0.f;
        #pragma unroll
        for (int kk2 = 0; kk2 < 4; ++kk2) {
            const int ms = kk2 >> 1, c = (kk2 & 1) * 4;
            unsigned pass0 = hi ? pk[ms][c + 0] : pk[ms][c + 2];
            unsigned pass1 = hi ? pk[ms][c + 1] : pk[ms][c + 3];
            unsigned sw0 = (unsigned)__shfl_xor((int)pass0, 32, 64);
            unsigned sw1 = (unsigned)__shfl_xor((int)pass1, 32, 64);
            union { bf16x8 v; unsigned u[4]; } bb;
            bb.u[0] = hi ? sw0 : pk[ms][c + 0];          // B[k2=16kk2+8hi+j][edge]
            bb.u[1] = hi ? sw1 : pk[ms][c + 1];
            bb.u[2] = hi ? pk[ms][c + 2] : sw0;
            bb.u[3] = hi ? pk[ms][c + 3] : sw1;
            #pragma unroll
            for (int mm = 0; mm < 2; ++mm)
                acc[mm] = __builtin_amdgcn_mfma_f32_32x32x16_bf16(w2r[kk2 * 2 + mm], bb.v, acc[mm], 0, 0, 0);
        }
        #pragma unroll
        for (int mm = 0; mm < 2; ++mm)                   // bias channel (k2=64)
            acc[mm] = __builtin_amdgcn_mfma_f32_32x32x16_bf16(w2r[8 + mm], cfrag, acc[mm], 0, 0, 0);

        // ---- layer 3: per-lane dot over held rows, 1 pair-reduce
        float p = 0.f;
        #pragma unroll
        for (int mm = 0; mm < 2; ++mm)
            #pragma unroll
            for (int q2 = 0; q2 < 4; ++q2) {
                f32x4 wv = *(const f32x4*)&w3s[f * 64 + mm * 32 + q2 * 8 + hi * 4];
                #pragma unroll
                for (int j = 0; j < 4; ++j)
                    p = fmaf(lrelu(acc[mm][q2 * 4 + j]), wv[j], p);
            }
        p += __shfl_xor(p, 32, 64);

        if (lane < 32) {
            int ee = tb + col;
            if (ee < n_edges) {
                float val = p + b3v;
                if (__builtin_isnan(ea)) val = __builtin_nanf("");
                out[(size_t)f * n_edges + ee] = val;
            }
        }

        t = tn; af = af2; at = at2;                      // wave-uniform
    }
}

extern "C" void kernel_launch(void* const* d_in, const int* in_sizes, int n_in,
                              void* d_out, int out_size, void* d_ws, size_t ws_size,
                              hipStream_t stream) {
    const float* edge_array = (const float*)d_in[0];
    const float* h_local    = (const float*)d_in[1];
    const float* h_global   = (const float*)d_in[2];
    const float* enc_local  = (const float*)d_in[3];
    const float* enc_global = (const float*)d_in[4];
    const float* W1 = (const float*)d_in[5];
    const float* b1 = (const float*)d_in[6];
    const float* W2 = (const float*)d_in[7];
    const float* b2 = (const float*)d_in[8];
    const float* W3 = (const float*)d_in[9];
    const float* b3 = (const float*)d_in[10];
    const int* addr_from = (const int*)d_in[11];
    const int* addr_to   = (const int*)d_in[12];
    int n_edges = in_sizes[11];
    int n_nodes = in_sizes[1] / 64;
    char* ws = (char*)d_ws;

    hipLaunchKernelGGL(prep_w, dim3(129), dim3(256), 0, stream,
                       W1, b1, W2, b2, W3, b3, h_global, enc_global, ws);

    int ntiles = (n_edges + 31) / 32;
    int nblk = 256;                                      // 1 persistent block/CU (8 waves)
    int nwpairs = (ntiles < nblk * NWAVE / 2) ? ntiles : nblk * NWAVE / 2;
    if (nwpairs < nblk * NWAVE / 2) nblk = (nwpairs * 2 + NWAVE - 1) / NWAVE;
    hipLaunchKernelGGL(main_kernel, dim3(nblk), dim3(512), 0, stream,
                       edge_array, h_local, enc_local, addr_from, addr_to,
                       ws, (float*)d_out, n_edges, n_nodes);
}

// Round 10
// 35.113 us; speedup vs baseline: 1.4665x; 1.4665x over previous
//
#include <hip/hip_runtime.h>

// LocalDecoder: per-edge gather + 2 stacked MLPs (256->64->64->1).
// 32x32x16 MFMA, edges on N=32: A = weight frag (M=out), B = x frag (N=edge).
// D layout (m74): col=lane&31 (edge), row=(reg&3)+8*(reg>>2)+4*(lane>>5).
// Layer1->2 redistribution: lane-pair (l, l^32) exchange via shfl_xor(32).
// R10: ea0 pass dropped (edge_array[4e] read direct in main).
//
// ws layout (bytes):
//   OFF_W1: bf16 W1frag[2][10][2][64][8]  (f, kk, mm, lane, j) = 40960
//   OFF_W2: bf16 W2frag[2][4][2][64][8]                        = 16384
//   OFF_B1: f32 bias1p[2][64]; OFF_B2: f32 b2[2][64]; OFF_W3: f32 w3[2][64]; OFF_B3: b3
//   off_hbf: bf16 hbf[n_nodes+1][64] (row n_nodes = 0)

#define OFF_W1 0
#define OFF_W2 40960
#define OFF_B1 57344
#define OFF_B2 57856
#define OFF_W3 58368
#define OFF_B3 58880
#define OFF_HBF 59392
#define NWAVE 8
#define LDS_TOTAL 58944
#define PREP_W_BLOCKS 114

typedef __attribute__((ext_vector_type(8))) short bf16x8;
typedef __attribute__((ext_vector_type(4))) float f32x4;
typedef __attribute__((ext_vector_type(16))) float f32x16;

__device__ inline short f2bf(float f) {                  // prep-side scalar RNE
    unsigned u = __builtin_bit_cast(unsigned, f);
    u += 0x7FFFu + ((u >> 16) & 1u);
    return (short)(u >> 16);
}

__device__ inline float4 ld4(const float* p, bool v) {
    if (v) return *(const float4*)p;
    return make_float4(0.f, 0.f, 0.f, 0.f);
}

__device__ inline unsigned cvt_pk(float lo, float hi) {  // 2xf32 -> packed 2xbf16 (RNE)
    unsigned r;
    asm("v_cvt_pk_bf16_f32 %0, %1, %2" : "=v"(r) : "v"(lo), "v"(hi));
    return r;
}

__device__ inline bf16x8 pack8(float4 a, float4 b) {
    union { bf16x8 v; unsigned u[4]; } r;
    r.u[0] = cvt_pk(a.x, a.y);
    r.u[1] = cvt_pk(a.z, a.w);
    r.u[2] = cvt_pk(b.x, b.y);
    r.u[3] = cvt_pk(b.z, b.w);
    return r.v;
}

__device__ inline float lrelu(float x) { return fmaxf(x, 0.01f * x); }

// ---------------- prep: W swizzle (32x32 frag layout) + bias fold + hbf
__global__ void prep_all(const float* __restrict__ W1, const float* __restrict__ b1,
                         const float* __restrict__ W2, const float* __restrict__ b2,
                         const float* __restrict__ W3, const float* __restrict__ b3,
                         const float* __restrict__ h_global, const float* __restrict__ enc_global,
                         const float* __restrict__ h_local, int n8,
                         short* __restrict__ hbf, char* __restrict__ ws) {
    int b = blockIdx.x;
    if (b >= PREP_W_BLOCKS) {                // h_local f32 -> bf16 (+ zero row)
        int i = (b - PREP_W_BLOCKS) * 256 + threadIdx.x;
        if (i < n8) {
            float4 a = ((const float4*)h_local)[2 * i];
            float4 c = ((const float4*)h_local)[2 * i + 1];
            ((bf16x8*)hbf)[i] = pack8(a, c);
        } else if (i < n8 + 8) {             // zero row (index n_nodes) for fill-0
            ((bf16x8*)hbf)[i] = (bf16x8){0, 0, 0, 0, 0, 0, 0, 0};
        }
        return;
    }
    int idx = b * 256 + threadIdx.x;
    short* w1f = (short*)(ws + OFF_W1);
    short* w2f = (short*)(ws + OFF_W2);
    float* bp1 = (float*)(ws + OFF_B1);
    float* bp2 = (float*)(ws + OFF_B2);
    float* wp3 = (float*)(ws + OFF_W3);
    float* bp3 = (float*)(ws + OFF_B3);
    if (idx < 20480) {                       // W1 frags: out=32mm+(l&31), kt=16kk+8(l>>5)+j
        int f = idx / 10240, r0 = idx % 10240;
        int kk = r0 / 1024, r1 = r0 % 1024;
        int mm = r1 / 512,  r2 = r1 % 512;
        int l = r2 / 8,     j = r2 % 8;
        int kt = kk * 16 + (l >> 5) * 8 + j;             // 0..159
        int r = (kt < 128) ? kt : kt + 64;               // enc_local rows live at 192..223
        int c = mm * 32 + (l & 31);
        w1f[idx] = f2bf(W1[(f * 256 + r) * 64 + c]);
    } else if (idx < 28672) {                // W2 frags
        int i2 = idx - 20480;
        int f = i2 / 4096, r0 = i2 % 4096;
        int kk2 = r0 / 1024, r1 = r0 % 1024;
        int mm = r1 / 512,  r2 = r1 % 512;
        int l = r2 / 8,     j = r2 % 8;
        int k = kk2 * 16 + (l >> 5) * 8 + j;
        int c = mm * 32 + (l & 31);
        w2f[i2] = f2bf(W2[(f * 64 + k) * 64 + c]);
    } else if (idx < 28800) {                // bias1' = b1 + globals @ W1 (full fp32)
        int i3 = idx - 28672; int f = i3 / 64, o = i3 % 64;
        float s = b1[f * 64 + o];
        for (int t = 0; t < 64; ++t) s += h_global[t] * W1[(f * 256 + 128 + t) * 64 + o];
        for (int t = 0; t < 32; ++t) s += enc_global[t] * W1[(f * 256 + 224 + t) * 64 + o];
        bp1[i3] = s;
    } else if (idx < 28928) {
        int i4 = idx - 28800; bp2[i4] = b2[i4];
    } else if (idx < 29056) {
        int i5 = idx - 28928; wp3[i5] = W3[i5];          // W3 is [2][64][1]
    } else if (idx < 29058) {
        bp3[idx - 29056] = b3[idx - 29056];
    }
}

// ---------------- main: persistent 8-wave blocks; 32 edges per wave-iteration
template<bool HBF>
__global__ __launch_bounds__(512, 4) void main_kernel(
        const float* __restrict__ edge_array,
        const float* __restrict__ h_local, const float* __restrict__ enc_local,
        const int* __restrict__ addr_from, const int* __restrict__ addr_to,
        const char* __restrict__ ws, const short* __restrict__ hbf,
        float* __restrict__ out, int n_edges, int n_nodes) {
    __shared__ __align__(16) char lds[LDS_TOTAL];
    const int tid = threadIdx.x;
    const int lane = tid & 63, wave = tid >> 6;
    const int col = lane & 31, hi = lane >> 5;
    const int niters = (n_edges + 31) >> 5;
    const int stride = gridDim.x * NWAVE;

    int t = blockIdx.x * NWAVE + wave;
    bool valid = t < niters;
    int af = 0, at = 0;
    if (valid) {                                         // index prefetch (breaks addr->node chain)
        int ec0 = t * 32 + col; if (ec0 >= n_edges) ec0 = n_edges - 1;
        af = addr_from[ec0]; at = addr_to[ec0];
    }

    // stage prepped W block into LDS once per block (linear float4 copy)
    #pragma unroll
    for (int it = 0; it < 7; ++it)
        ((float4*)lds)[it * 512 + tid] = ((const float4*)ws)[it * 512 + tid];
    if (tid < 100)
        ((float4*)(lds + 57344))[tid] = ((const float4*)(ws + 57344))[tid];
    __syncthreads();                                     // only block-wide barrier

    const float b3v0 = ((const float*)(lds + OFF_B3))[0];
    const float b3v1 = ((const float*)(lds + OFF_B3))[1];

    while (valid) {
        int tb = t * 32;
        int ec = tb + col; if (ec >= n_edges) ec = n_edges - 1;

        // ---- gather: 13 naked loads (HBF), k = 16kk + 8hi + j
        bf16x8 a1[10];
        float4 e0, e1, e2, e3;
        float ea;
        if (HBF) {
            unsigned ra = (unsigned)af < (unsigned)n_nodes ? (unsigned)af : (unsigned)n_nodes;
            unsigned rt = (unsigned)at < (unsigned)n_nodes ? (unsigned)at : (unsigned)n_nodes;
            const short* pf = hbf + (size_t)ra * 64 + hi * 8;
            const short* pt = hbf + (size_t)rt * 64 + hi * 8;
            a1[0] = *(const bf16x8*)pf;        a1[1] = *(const bf16x8*)(pf + 16);
            a1[2] = *(const bf16x8*)(pf + 32); a1[3] = *(const bf16x8*)(pf + 48);
            a1[4] = *(const bf16x8*)pt;        a1[5] = *(const bf16x8*)(pt + 16);
            a1[6] = *(const bf16x8*)(pt + 32); a1[7] = *(const bf16x8*)(pt + 48);
            const float* pe = enc_local + (size_t)ec * 32 + hi * 8;
            e0 = *(const float4*)pe;        e1 = *(const float4*)(pe + 4);
            e2 = *(const float4*)(pe + 16); e3 = *(const float4*)(pe + 20);
            ea = edge_array[4 * (size_t)ec];
        } else {
            bool afv = (unsigned)af < (unsigned)n_nodes;
            bool atv = (unsigned)at < (unsigned)n_nodes;
            const float* pf = h_local + (size_t)(afv ? af : 0) * 64 + hi * 8;
            const float* pt = h_local + (size_t)(atv ? at : 0) * 64 + hi * 8;
            #pragma unroll
            for (int kk = 0; kk < 4; ++kk) {
                a1[kk]     = pack8(ld4(pf + 16 * kk, afv), ld4(pf + 16 * kk + 4, afv));
                a1[kk + 4] = pack8(ld4(pt + 16 * kk, atv), ld4(pt + 16 * kk + 4, atv));
            }
            const float* pe = enc_local + (size_t)ec * 32 + hi * 8;
            e0 = *(const float4*)pe;        e1 = *(const float4*)(pe + 4);
            e2 = *(const float4*)(pe + 16); e3 = *(const float4*)(pe + 20);
            ea = edge_array[4 * (size_t)ec];
        }

        // prefetch NEXT iteration's indices (latency hides under this tile's MFMAs)
        int tn = t + stride;
        bool vnext = tn < niters;
        int af2 = 0, at2 = 0;
        if (vnext) {
            int ec2 = tn * 32 + col; if (ec2 >= n_edges) ec2 = n_edges - 1;
            af2 = addr_from[ec2]; at2 = addr_to[ec2];
        }

        a1[8] = pack8(e0, e1);                           // enc -> bf16 frags (kk 8,9)
        a1[9] = pack8(e2, e3);

        #pragma unroll
        for (int f = 0; f < 2; ++f) {
            // ---- layer 1: D[out][edge]; bias as C-init
            f32x16 acc[2];
            #pragma unroll
            for (int mm = 0; mm < 2; ++mm)
                #pragma unroll
                for (int q2 = 0; q2 < 4; ++q2) {
                    f32x4 v = *(const f32x4*)(lds + OFF_B1 + (f * 64 + mm * 32 + q2 * 8 + hi * 4) * 4);
                    acc[mm][q2 * 4 + 0] = v[0]; acc[mm][q2 * 4 + 1] = v[1];
                    acc[mm][q2 * 4 + 2] = v[2]; acc[mm][q2 * 4 + 3] = v[3];
                }
            #pragma unroll
            for (int kk = 0; kk < 10; ++kk)
                #pragma unroll
                for (int mm = 0; mm < 2; ++mm) {
                    bf16x8 w = *(const bf16x8*)(lds + OFF_W1 + (((f * 10 + kk) * 2 + mm) * 64 + lane) * 16);
                    acc[mm] = __builtin_amdgcn_mfma_f32_32x32x16_bf16(w, a1[kk], acc[mm], 0, 0, 0);
                }

            // lrelu + pack: pk[mm][i] = bf16 pair of rows (reg 2i, 2i+1)
            unsigned pk[2][8];
            #pragma unroll
            for (int mm = 0; mm < 2; ++mm)
                #pragma unroll
                for (int i = 0; i < 8; ++i)
                    pk[mm][i] = cvt_pk(lrelu(acc[mm][2 * i]), lrelu(acc[mm][2 * i + 1]));

            // ---- layer 2: lane-pair redistribution, b2 as C-init
            f32x16 acc2[2];
            #pragma unroll
            for (int mm = 0; mm < 2; ++mm)
                #pragma unroll
                for (int q2 = 0; q2 < 4; ++q2) {
                    f32x4 v = *(const f32x4*)(lds + OFF_B2 + (f * 64 + mm * 32 + q2 * 8 + hi * 4) * 4);
                    acc2[mm][q2 * 4 + 0] = v[0]; acc2[mm][q2 * 4 + 1] = v[1];
                    acc2[mm][q2 * 4 + 2] = v[2]; acc2[mm][q2 * 4 + 3] = v[3];
                }
            #pragma unroll
            for (int kk2 = 0; kk2 < 4; ++kk2) {
                const int ms = kk2 >> 1, c = (kk2 & 1) * 4;
                unsigned pass0 = hi ? pk[ms][c + 0] : pk[ms][c + 2];
                unsigned pass1 = hi ? pk[ms][c + 1] : pk[ms][c + 3];
                unsigned sw0 = (unsigned)__shfl_xor((int)pass0, 32, 64);
                unsigned sw1 = (unsigned)__shfl_xor((int)pass1, 32, 64);
                union { bf16x8 v; unsigned u[4]; } bb;
                bb.u[0] = hi ? sw0 : pk[ms][c + 0];      // B[k=16kk2+8hi+j][edge]
                bb.u[1] = hi ? sw1 : pk[ms][c + 1];
                bb.u[2] = hi ? pk[ms][c + 2] : sw0;
                bb.u[3] = hi ? pk[ms][c + 3] : sw1;
                #pragma unroll
                for (int mm = 0; mm < 2; ++mm) {
                    bf16x8 w = *(const bf16x8*)(lds + OFF_W2 + (((f * 4 + kk2) * 2 + mm) * 64 + lane) * 16);
                    acc2[mm] = __builtin_amdgcn_mfma_f32_32x32x16_bf16(w, bb.v, acc2[mm], 0, 0, 0);
                }
            }

            // ---- layer 3: per-lane dot over 32 held rows, 1 pair-reduce
            float p = 0.f;
            #pragma unroll
            for (int mm = 0; mm < 2; ++mm)
                #pragma unroll
                for (int q2 = 0; q2 < 4; ++q2) {
                    f32x4 wv = *(const f32x4*)(lds + OFF_W3 + (f * 64 + mm * 32 + q2 * 8 + hi * 4) * 4);
                    #pragma unroll
                    for (int j = 0; j < 4; ++j)
                        p = fmaf(lrelu(acc2[mm][q2 * 4 + j]), wv[j], p);
                }
            p += __shfl_xor(p, 32, 64);

            if (lane < 32) {                             // coalesced 32-lane store
                int ee = tb + col;
                if (ee < n_edges) {
                    float val = p + (f == 0 ? b3v0 : b3v1);
                    if (__builtin_isnan(ea)) val = __builtin_nanf("");
                    out[f * n_edges + ee] = val;
                }
            }
        }

        t = tn; valid = vnext; af = af2; at = at2;       // wave-uniform
    }
}

extern "C" void kernel_launch(void* const* d_in, const int* in_sizes, int n_in,
                              void* d_out, int out_size, void* d_ws, size_t ws_size,
                              hipStream_t stream) {
    const float* edge_array = (const float*)d_in[0];
    const float* h_local    = (const float*)d_in[1];
    const float* h_global   = (const float*)d_in[2];
    const float* enc_local  = (const float*)d_in[3];
    const float* enc_global = (const float*)d_in[4];
    const float* W1 = (const float*)d_in[5];
    const float* b1 = (const float*)d_in[6];
    const float* W2 = (const float*)d_in[7];
    const float* b2 = (const float*)d_in[8];
    const float* W3 = (const float*)d_in[9];
    const float* b3 = (const float*)d_in[10];
    const int* addr_from = (const int*)d_in[11];
    const int* addr_to   = (const int*)d_in[12];
    int n_edges = in_sizes[11];
    int n_nodes = in_sizes[1] / 64;
    int n8 = n_nodes * 8;
    char* ws = (char*)d_ws;

    size_t need = (size_t)OFF_HBF + (size_t)(n_nodes + 1) * 128;
    bool use_hbf = ws_size >= need;
    short* hbf = (short*)(ws + OFF_HBF);

    int hb = (n8 + 8 + 255) / 256;
    int prep_blocks = PREP_W_BLOCKS + (use_hbf ? hb : 0);
    hipLaunchKernelGGL(prep_all, dim3(prep_blocks), dim3(256), 0, stream,
                       W1, b1, W2, b2, W3, b3, h_global, enc_global,
                       h_local, use_hbf ? n8 : 0, hbf, ws);

    int niters = (n_edges + 31) / 32;
    int nblk = 512;                                      // 2 persistent blocks/CU
    if (nblk * NWAVE > niters) nblk = (niters + NWAVE - 1) / NWAVE;
    if (use_hbf) {
        hipLaunchKernelGGL((main_kernel<true>), dim3(nblk), dim3(512), 0, stream,
                           edge_array, h_local, enc_local, addr_from, addr_to,
                           ws, hbf, (float*)d_out, n_edges, n_nodes);
    } else {
        hipLaunchKernelGGL((main_kernel<false>), dim3(nblk), dim3(512), 0, stream,
                           edge_array, h_local, enc_local, addr_from, addr_to,
                           ws, hbf, (float*)d_out, n_edges, n_nodes);
    }
}